// Round 1
// baseline (9.710 us; speedup 1.0000x reference)
//
#include <hip/hip_runtime.h>

// Problem constants (match reference)
#define N_LOCS_C 500000
#define NN 100          // NUM_NEAREST
#define KK 16           // K
#define LL 8192         // L

__global__ __launch_bounds__(256)
void knn_pop_sampler_kernel(const int*   __restrict__ trg_seq,   // [L,2]
                            const float* __restrict__ u,         // [L,K]
                            const int*   __restrict__ nearby,    // [N_LOCS,NN]
                            const float* __restrict__ freqs,     // [N_LOCS,NN]
                            const float* __restrict__ cum,       // [N_LOCS,NN]
                            float*       __restrict__ out_samples, // [L,K] (int values as float)
                            float*       __restrict__ out_probs)   // [L,K]
{
    int t = blockIdx.x * blockDim.x + threadIdx.x;   // 0 .. L*K-1
    if (t >= LL * KK) return;

    int i = t >> 4;          // row (K = 16)
    // row index into the tables
    int loc = trg_seq[2 * i + 1] - 1;
    loc = min(max(loc, 0), N_LOCS_C - 1);

    float x = u[t];

    // bisect_left == count of elements strictly < x (row is sorted ascending)
    const float* crow = cum + (long long)loc * NN;   // 400B rows -> 16B aligned
    int cnt = 0;
#pragma unroll
    for (int e = 0; e < NN; e += 4) {
        float4 v = *reinterpret_cast<const float4*>(crow + e);
        cnt += (v.x < x) + (v.y < x) + (v.z < x) + (v.w < x);
    }
    int idx = min(cnt, NN - 1);

    long long base = (long long)loc * NN + idx;
    out_samples[t] = (float)nearby[base];
    out_probs[t]   = freqs[base];
}

extern "C" void kernel_launch(void* const* d_in, const int* in_sizes, int n_in,
                              void* d_out, int out_size, void* d_ws, size_t ws_size,
                              hipStream_t stream) {
    const int*   trg_seq = (const int*)  d_in[0];   // [L,2] int32
    // d_in[1] is k == 16 (compile-time constant here)
    const float* u       = (const float*)d_in[2];   // [L,K] f32
    const int*   nearby  = (const int*)  d_in[3];   // [N_LOCS,NN] int32
    const float* freqs   = (const float*)d_in[4];   // [N_LOCS,NN] f32
    const float* cum     = (const float*)d_in[5];   // [N_LOCS,NN] f32

    float* out = (float*)d_out;
    float* out_samples = out;            // first L*K
    float* out_probs   = out + LL * KK;  // second L*K

    const int total  = LL * KK;          // 131072
    const int block  = 256;
    const int grid   = (total + block - 1) / block;  // 512
    knn_pop_sampler_kernel<<<grid, block, 0, stream>>>(
        trg_seq, u, nearby, freqs, cum, out_samples, out_probs);
}

// Round 2
// 9.413 us; speedup vs baseline: 1.0316x; 1.0316x over previous
//
#include <hip/hip_runtime.h>

// Problem constants (match reference)
#define N_LOCS_C 500000
#define NN 100          // NUM_NEAREST
#define KK 16           // K
#define LL 8192         // L

__global__ __launch_bounds__(256)
void knn_pop_sampler_kernel(const int*   __restrict__ trg_seq,   // [L,2]
                            const float* __restrict__ u,         // [L,K]
                            const int*   __restrict__ nearby,    // [N_LOCS,NN]
                            const float* __restrict__ freqs,     // [N_LOCS,NN]
                            const float* __restrict__ cum,       // [N_LOCS,NN]
                            float*       __restrict__ out_samples, // [L,K] (int ids as float)
                            float*       __restrict__ out_probs)   // [L,K]
{
    int t = blockIdx.x * blockDim.x + threadIdx.x;   // 0 .. L*K-1
    if (t >= LL * KK) return;

    int i = t >> 4;          // row (K = 16)
    int j = t & 15;          // lane-in-group (16 threads share a row)

    int loc = trg_seq[2 * i + 1] - 1;
    loc = min(max(loc, 0), N_LOCS_C - 1);

    float x = u[t];

    long long rowbase = (long long)loc * NN;

    // ---- Prefetch the gather rows while the cum-row scan is in flight ----
    // Rows span 400B = up to 8 distinct 64B lines. 16 lanes touch every 7th
    // element (28B stride < 64B line) so every line of both rows is fetched.
    int e = j * 7; if (e > NN - 1) e = NN - 1;
    int   pf_n = nearby[rowbase + e];
    float pf_f = freqs[rowbase + e];

    // ---- bisect_left == count of elements strictly < x (ascending row) ----
    const float* crow = cum + rowbase;               // 400B rows, 16B aligned
    int cnt = 0;
#pragma unroll
    for (int q = 0; q < NN; q += 4) {
        float4 v = *reinterpret_cast<const float4*>(crow + q);
        cnt += (v.x < x) + (v.y < x) + (v.z < x) + (v.w < x);
    }
    int idx = min(cnt, NN - 1);

    // Keep the prefetch results live (prevents DCE) without affecting output.
    asm volatile("" :: "v"(pf_n), "v"(pf_f));

    // These now hit L1/L2 thanks to the prefetch above.
    long long base = rowbase + idx;
    out_samples[t] = (float)nearby[base];
    out_probs[t]   = freqs[base];
}

extern "C" void kernel_launch(void* const* d_in, const int* in_sizes, int n_in,
                              void* d_out, int out_size, void* d_ws, size_t ws_size,
                              hipStream_t stream) {
    const int*   trg_seq = (const int*)  d_in[0];   // [L,2] int32
    // d_in[1] is k == 16 (compile-time constant here)
    const float* u       = (const float*)d_in[2];   // [L,K] f32
    const int*   nearby  = (const int*)  d_in[3];   // [N_LOCS,NN] int32
    const float* freqs   = (const float*)d_in[4];   // [N_LOCS,NN] f32
    const float* cum     = (const float*)d_in[5];   // [N_LOCS,NN] f32

    float* out = (float*)d_out;
    float* out_samples = out;            // first L*K
    float* out_probs   = out + LL * KK;  // second L*K

    const int total  = LL * KK;          // 131072
    const int block  = 256;
    const int grid   = (total + block - 1) / block;  // 512
    knn_pop_sampler_kernel<<<grid, block, 0, stream>>>(
        trg_seq, u, nearby, freqs, cum, out_samples, out_probs);
}